// Round 10
// baseline (234.594 us; speedup 1.0000x reference)
//
#include <hip/hip_runtime.h>
#include <cstdint>

typedef unsigned short u16;
typedef uint32_t u32;
typedef __attribute__((ext_vector_type(8))) short bf16x8;
typedef __attribute__((ext_vector_type(4))) short bf16x4;
typedef __attribute__((ext_vector_type(4))) float f32x4;

#define NB 4
#define NT 2048
#define NC 1024
#define NH 16
#define ND 64
#define NM (NB*NT)      // 8192
#define N3C (3*NC)      // 3072
#define NQT (NT/64)     // 32 q-tiles per (b,h)

// Q scale: 1/sqrt(64) * log2(e)  (softmax runs in log2 domain -> exp2)
#define QSCALE 0.18033688011112042f

static __device__ __forceinline__ u16 f2bf(float f){
  union { float f; uint32_t u; } v; v.f = f;
  return (u16)((v.u + 0x7fffu + ((v.u >> 16) & 1u)) >> 16);
}

// async 16B global->LDS (LDS dest is wave-uniform base + lane*16)
static __device__ __forceinline__ void gld_lds16(void* lds, const void* g){
  auto lp = reinterpret_cast<__attribute__((address_space(3))) uint32_t*>(
      reinterpret_cast<uintptr_t>(lds));
  auto gp = reinterpret_cast<__attribute__((address_space(1))) uint32_t*>(
      reinterpret_cast<uintptr_t>(g));
  __builtin_amdgcn_global_load_lds(gp, lp, 16, 0, 0);
}

static __device__ __forceinline__ f32x4 mfma16(bf16x4 a, bf16x4 b, f32x4 c){
#if __has_builtin(__builtin_amdgcn_mfma_f32_16x16x16bf16_1k)
  return __builtin_amdgcn_mfma_f32_16x16x16bf16_1k(a, b, c, 0, 0, 0);
#else
  asm("v_mfma_f32_16x16x16_bf16 %0, %1, %2, %0" : "+v"(c) : "v"(a), "v"(b));
  return c;
#endif
}

// ---------------- elementwise cast fp32 -> bf16 ----------------
__global__ __launch_bounds__(256) void k_cast(const float* __restrict__ in,
                                              u16* __restrict__ out){
  const int i = (blockIdx.x * 256 + threadIdx.x) * 4;
  const float4 vv = *reinterpret_cast<const float4*>(in + i);
  union { u16 s[4]; uint64_t u; } pk;
  pk.s[0] = f2bf(vv.x); pk.s[1] = f2bf(vv.y);
  pk.s[2] = f2bf(vv.z); pk.s[3] = f2bf(vv.w);
  *reinterpret_cast<uint64_t*>(out + i) = pk.u;
}

// ---------------- tiled transpose + cast: in[R][Cc] fp32 -> out[Cc][R] bf16 ----------------
__global__ __launch_bounds__(256) void k_transpose_cast(const float* __restrict__ in,
                                                        u16* __restrict__ out,
                                                        int R, int Cc){
  __shared__ float tile[32][33];
  const int bx = blockIdx.x * 32, by = blockIdx.y * 32;
  const int tx = threadIdx.x, ty = threadIdx.y;
#pragma unroll
  for (int i = 0; i < 32; i += 8)
    tile[ty + i][tx] = in[(size_t)(by + ty + i) * Cc + bx + tx];
  __syncthreads();
#pragma unroll
  for (int i = 0; i < 32; i += 8)
    out[(size_t)(bx + ty + i) * R + by + tx] = f2bf(tile[tx][ty + i]);
}

// ---------------- shared GEMM main loop: C[128x128] tile, A[M][K] * Bt[N][K]^T ----------------
static __device__ __forceinline__ void gemm_mainloop(
    const u16* __restrict__ A, const u16* __restrict__ Bt, int K,
    int m0, int n0, u16* As, u16* Bs, f32x4 acc[4][4])
{
  const int tid = threadIdx.x;
  const int wave = tid >> 6, lane = tid & 63;
  const int wm = wave >> 1, wn = wave & 1;
  const int o0 = tid * 8, o1 = o0 + 2048;           // elem offsets in the 128x32 tile
  const u16* Ag0 = A  + (size_t)(m0 + (o0 >> 5)) * K + (o0 & 31);
  const u16* Ag1 = A  + (size_t)(m0 + (o1 >> 5)) * K + (o1 & 31);
  const u16* Bg0 = Bt + (size_t)(n0 + (o0 >> 5)) * K + (o0 & 31);
  const u16* Bg1 = Bt + (size_t)(n0 + (o1 >> 5)) * K + (o1 & 31);
  u16* AsW = As + wave * 512;   // wave-uniform LDS base (1024 B per wave)
  u16* BsW = Bs + wave * 512;
  const int kb = (lane >> 4) * 8, rl = lane & 15;

  for (int kt = 0; kt < K; kt += 32){
    gld_lds16(AsW,        Ag0 + kt);
    gld_lds16(AsW + 2048, Ag1 + kt);
    gld_lds16(BsW,        Bg0 + kt);
    gld_lds16(BsW + 2048, Bg1 + kt);
    __syncthreads();
    bf16x8 af[4], bfr[4];
#pragma unroll
    for (int i = 0; i < 4; i++){
      af[i]  = *reinterpret_cast<const bf16x8*>(&As[(wm * 64 + i * 16 + rl) * 32 + kb]);
      bfr[i] = *reinterpret_cast<const bf16x8*>(&Bs[(wn * 64 + i * 16 + rl) * 32 + kb]);
    }
#pragma unroll
    for (int i = 0; i < 4; i++)
#pragma unroll
      for (int j = 0; j < 4; j++)
        acc[i][j] = __builtin_amdgcn_mfma_f32_16x16x32_bf16(af[i], bfr[j], acc[i][j], 0, 0, 0);
    __syncthreads();
  }
}

// ---------------- GEMM 1: x @ w_qkv + b_qkv -> Q (scaled), K (swizzled), V (transposed+swizzled) ----------------
// Q: [b,h,t,d] standard, values * QSCALE
// K: per (b,h): tile kt (4096 elems): (t&63)*64 + (d ^ ((t&7)<<3))
// V: per (b,h): tile kt (4096 elems): d*64 + (((t>>2)&15 ^ (d&7))<<2) + (t&3)   [transposed]
__global__ __launch_bounds__(256) void k_gemm_qkv(
    const u16* __restrict__ A, const u16* __restrict__ Bt,
    const float* __restrict__ bias,
    u16* __restrict__ qo, u16* __restrict__ ko, u16* __restrict__ vo)
{
  __shared__ u16 As[128 * 32], Bs[128 * 32];
  f32x4 acc[4][4] = {};
  const int m0 = blockIdx.y * 128, n0 = blockIdx.x * 128;
  gemm_mainloop(A, Bt, NC, m0, n0, As, Bs, acc);

  const int tid = threadIdx.x;
  const int wave = tid >> 6, lane = tid & 63;
  const int wm = wave >> 1, wn = wave & 1;
  const int rl = lane & 15, rg = lane >> 4;
  const int which = n0 >> 10;   // uniform per block: 0=Q 1=K 2=V
  if (which == 2){
    // V: pack 4 consecutive t (r=0..3, t&3=r) into one 8B store
#pragma unroll
    for (int j = 0; j < 4; j++){
      const int n = n0 + wn * 64 + j * 16 + rl;
      const int cc = n & 1023;
      const int h = cc >> 6, d = cc & 63;
      const float bb = bias[n];
#pragma unroll
      for (int i = 0; i < 4; i++){
        const int mb = m0 + wm * 64 + i * 16 + rg * 4;
        const int b = mb >> 11, t0 = mb & 2047;
        const size_t bhb = ((size_t)(b * NH + h)) * NT * ND;
        union { u16 s[4]; uint64_t u; } pk4;
#pragma unroll
        for (int r = 0; r < 4; r++) pk4.s[r] = f2bf(acc[i][j][r] + bb);
        *reinterpret_cast<uint64_t*>(
          &vo[bhb + (size_t)(t0 >> 6) * 4096 + d * 64 + ((((t0 >> 2) & 15) ^ (d & 7)) << 2)]) = pk4.u;
      }
    }
  } else {
#pragma unroll
    for (int j = 0; j < 4; j++){
      const int n = n0 + wn * 64 + j * 16 + rl;
      const int cc = n & 1023;
      const int h = cc >> 6, d = cc & 63;
      const float bb = bias[n];
#pragma unroll
      for (int i = 0; i < 4; i++){
#pragma unroll
        for (int r = 0; r < 4; r++){
          const int m = m0 + wm * 64 + i * 16 + rg * 4 + r;
          const int b = m >> 11, t = m & 2047;
          const size_t bhb = ((size_t)(b * NH + h)) * NT * ND;
          const float val = acc[i][j][r] + bb;
          if (which == 0){
            qo[bhb + (size_t)t * ND + d] = f2bf(val * QSCALE);
          } else {
            ko[bhb + (size_t)(t >> 6) * 4096 + (t & 63) * 64 + (d ^ ((t & 7) << 3))] = f2bf(val);
          }
        }
      }
    }
  }
}

// ---------------- GEMM 2: attn_out @ w_proj + b_proj -> fp32 out ----------------
__global__ __launch_bounds__(256) void k_gemm_proj(
    const u16* __restrict__ A, const u16* __restrict__ Bt,
    const float* __restrict__ bias, float* __restrict__ out)
{
  __shared__ u16 As[128 * 32], Bs[128 * 32];
  f32x4 acc[4][4] = {};
  const int m0 = blockIdx.y * 128, n0 = blockIdx.x * 128;
  gemm_mainloop(A, Bt, NC, m0, n0, As, Bs, acc);

  const int tid = threadIdx.x;
  const int wave = tid >> 6, lane = tid & 63;
  const int wm = wave >> 1, wn = wave & 1;
  const int rl = lane & 15, rg = lane >> 4;
#pragma unroll
  for (int i = 0; i < 4; i++){
#pragma unroll
    for (int r = 0; r < 4; r++){
      const int m = m0 + wm * 64 + i * 16 + rg * 4 + r;
#pragma unroll
      for (int j = 0; j < 4; j++){
        const int n = n0 + wn * 64 + j * 16 + rl;
        out[(size_t)m * NC + n] = acc[i][j][r] + bias[n];
      }
    }
  }
}

// ---------------- flash helpers ----------------
// S^T = K Q^T : s[nf] holds S^T[k = nf*16 + g*4 + r][q = cl]
static __device__ __forceinline__ void qkt(const u16* __restrict__ KsC,
                                           bf16x8 qf0, bf16x8 qf1,
                                           int cl, int g, f32x4 s[4])
{
  __builtin_amdgcn_s_setprio(1);
#pragma unroll
  for (int nf = 0; nf < 4; nf++){
    const int kj = nf * 16 + cl;
    const u16* krow = &KsC[kj * 64];
    const bf16x8 kf0 = *reinterpret_cast<const bf16x8*>(&krow[((0 + g) ^ (kj & 7)) * 8]);
    const bf16x8 kf1 = *reinterpret_cast<const bf16x8*>(&krow[((4 + g) ^ (kj & 7)) * 8]);
    f32x4 a = {};
    a = __builtin_amdgcn_mfma_f32_16x16x32_bf16(kf0, qf0, a, 0, 0, 0);
    a = __builtin_amdgcn_mfma_f32_16x16x32_bf16(kf1, qf1, a, 0, 0, 0);
    s[nf] = a;
  }
  __builtin_amdgcn_s_setprio(0);
}

static __device__ __forceinline__ void maskdiag(f32x4 s[4], int wave, int cl, int g){
  const int qrl = wave * 16 + cl;
#pragma unroll
  for (int nf = 0; nf < 4; nf++)
#pragma unroll
    for (int r = 0; r < 4; r++)
      if (nf * 16 + g * 4 + r > qrl) s[nf][r] = -3e38f;
}

// online softmax (log2 domain, defer-max THR=8); emits bf16 A-frag words pk[8]
static __device__ __forceinline__ void softmax_pk(
    f32x4 s[4], f32x4 o[4], float& mrun, float& lrun, int g, u32 pk[8])
{
  // tree max (depth 4)
  const float t0 = fmaxf(fmaxf(s[0][0], s[0][1]), fmaxf(s[0][2], s[0][3]));
  const float t1 = fmaxf(fmaxf(s[1][0], s[1][1]), fmaxf(s[1][2], s[1][3]));
  const float t2 = fmaxf(fmaxf(s[2][0], s[2][1]), fmaxf(s[2][2], s[2][3]));
  const float t3 = fmaxf(fmaxf(s[3][0], s[3][1]), fmaxf(s[3][2], s[3][3]));
  float rmax = fmaxf(fmaxf(t0, t1), fmaxf(t2, t3));
  rmax = fmaxf(rmax, __shfl_xor(rmax, 16));
  rmax = fmaxf(rmax, __shfl_xor(rmax, 32));
  // defer-max: only rescale when the row max grew by >8 (P bounded by 2^8)
  if (!__all(rmax <= mrun + 8.0f)){
    const float mnew = fmaxf(mrun, rmax);
    const float alpha = exp2f(mrun - mnew);
    mrun = mnew;
    lrun *= alpha;
    const float a0 = __shfl(alpha, g * 4 + 0);
    const float a1 = __shfl(alpha, g * 4 + 1);
    const float a2 = __shfl(alpha, g * 4 + 2);
    const float a3 = __shfl(alpha, g * 4 + 3);
#pragma unroll
    for (int fo = 0; fo < 4; fo++){
      o[fo][0] *= a0; o[fo][1] *= a1; o[fo][2] *= a2; o[fo][3] *= a3;
    }
  }
#pragma unroll
  for (int nf = 0; nf < 4; nf++)
#pragma unroll
    for (int r = 0; r < 4; r++)
      s[nf][r] = exp2f(s[nf][r] - mrun);
  // tree sum
  const float u0 = (s[0][0] + s[0][1]) + (s[0][2] + s[0][3]);
  const float u1 = (s[1][0] + s[1][1]) + (s[1][2] + s[1][3]);
  const float u2 = (s[2][0] + s[2][1]) + (s[2][2] + s[2][3]);
  const float u3 = (s[3][0] + s[3][1]) + (s[3][2] + s[3][3]);
  float rs = (u0 + u1) + (u2 + u3);
  rs += __shfl_xor(rs, 16);
  rs += __shfl_xor(rs, 32);
  lrun += rs;
#pragma unroll
  for (int nf = 0; nf < 4; nf++){
    asm("v_cvt_pk_bf16_f32 %0, %1, %2" : "=v"(pk[2*nf  ]) : "v"(s[nf][0]), "v"(s[nf][1]));
    asm("v_cvt_pk_bf16_f32 %0, %1, %2" : "=v"(pk[2*nf+1]) : "v"(s[nf][2]), "v"(s[nf][3]));
  }
}

// single-state softmax + PV
static __device__ __forceinline__ void sm_pv(
    f32x4 s[4], f32x4 o[4], float& mrun, float& lrun,
    const u16* __restrict__ VtC, int cl, int g)
{
  u32 pk[8];
  softmax_pk(s, o, mrun, lrun, g, pk);
  __builtin_amdgcn_s_setprio(1);
#pragma unroll
  for (int fo = 0; fo < 4; fo++){
    const int d = fo * 16 + cl;
#pragma unroll
    for (int nf = 0; nf < 4; nf++){
      const bf16x4 vf = *reinterpret_cast<const bf16x4*>(
          &VtC[d * 64 + (((nf * 4 + g) ^ (d & 7)) << 2)]);
      union { u32 u[2]; bf16x4 v; } pa;
      pa.u[0] = pk[2*nf]; pa.u[1] = pk[2*nf+1];
      o[fo] = mfma16(pa.v, vf, o[fo]);
    }
  }
  __builtin_amdgcn_s_setprio(0);
}

// ---------------- causal flash attention: one KV sweep serves q-tiles {px, 31-px} ----------------
// Double-buffered staging, raw s_barrier + counted vmcnt (loads in flight across barriers).
// Overlap region (t <= qt1): fused dual-state body shares K/V LDS reads between both states.
__global__ __launch_bounds__(256) void k_flash(
    const u16* __restrict__ q, const u16* __restrict__ k,
    const u16* __restrict__ v, u16* __restrict__ ao)
{
  __shared__ u16 Ks[2][4096];   // [buf][kj*64 + swz-d], 16B-chunk swizzle: chunk' = chunk ^ (kj&7)
  __shared__ u16 Vt[2][4096];   // [buf][d*64 + swz-kj], 8B-chunk swizzle
  const int tid = threadIdx.x, wave = tid >> 6, lane = tid & 63;
  const int cl = lane & 15, g = lane >> 4;
  const int c0 = wave * 2;
  const int px = blockIdx.x, bh = blockIdx.y;
  const int qt1 = px, qt2 = NQT - 1 - px;
  const int ntot = qt2 + 1;
  const size_t base = (size_t)bh * NT * ND;
  const u16* kg0 = k + base;
  const u16* vg0 = v + base;

  // Q frags for both tiles: lane holds Q[q=cl][d=g*8+j]
  bf16x8 q1f0, q1f1, q2f0, q2f1;
  {
    const u16* qr1 = q + base + (size_t)(qt1 * 64 + wave * 16 + cl) * ND;
    q1f0 = *reinterpret_cast<const bf16x8*>(qr1 + g * 8);
    q1f1 = *reinterpret_cast<const bf16x8*>(qr1 + 32 + g * 8);
    const u16* qr2 = q + base + (size_t)(qt2 * 64 + wave * 16 + cl) * ND;
    q2f0 = *reinterpret_cast<const bf16x8*>(qr2 + g * 8);
    q2f1 = *reinterpret_cast<const bf16x8*>(qr2 + 32 + g * 8);
  }
  asm volatile("" : "+v"(q1f0), "+v"(q1f1), "+v"(q2f0), "+v"(q2f1));

  f32x4 o1[4] = {}, o2[4] = {};
  float m1 = -1e30f, l1 = 0.f, m2 = -1e30f, l2 = 0.f;

  // prologue: stage tile 0 -> buf 0 (4 gld_lds16 per wave)
  gld_lds16(&Ks[0][(c0    ) * 512], kg0 + (c0    ) * 512 + lane * 8);
  gld_lds16(&Ks[0][(c0 + 1) * 512], kg0 + (c0 + 1) * 512 + lane * 8);
  gld_lds16(&Vt[0][(c0    ) * 512], vg0 + (c0    ) * 512 + lane * 8);
  gld_lds16(&Vt[0][(c0 + 1) * 512], vg0 + (c0 + 1) * 512 + lane * 8);

  for (int t = 0; t < ntot; ++t){
    const int cur = t & 1, nxt = cur ^ 1;
    if (t + 1 < ntot){
      const u16* kg = kg0 + (size_t)(t + 1) * 4096;
      const u16* vg = vg0 + (size_t)(t + 1) * 4096;
      gld_lds16(&Ks[nxt][(c0    ) * 512], kg + (c0    ) * 512 + lane * 8);
      gld_lds16(&Ks[nxt][(c0 + 1) * 512], kg + (c0 + 1) * 512 + lane * 8);
      gld_lds16(&Vt[nxt][(c0    ) * 512], vg + (c0    ) * 512 + lane * 8);
      gld_lds16(&Vt[nxt][(c0 + 1) * 512], vg + (c0 + 1) * 512 + lane * 8);
      asm volatile("s_waitcnt vmcnt(4)" ::: "memory");   // own tile-t loads done; t+1 in flight
    } else {
      asm volatile("s_waitcnt vmcnt(0)" ::: "memory");
    }
    __builtin_amdgcn_sched_barrier(0);
    __builtin_amdgcn_s_barrier();    // raw: no implicit vmcnt(0) drain

    const u16* KsC = Ks[cur];
    const u16* VtC = Vt[cur];

    if (t <= qt1){
      // ---- fused dual-state body: K frags loaded once, feed both QK^T ----
      f32x4 s1[4], s2[4];
      __builtin_amdgcn_s_setprio(1);
#pragma unroll
      for (int nf = 0; nf < 4; nf++){
        const int kj = nf * 16 + cl;
        const u16* krow = &KsC[kj * 64];
        const bf16x8 kf0 = *reinterpret_cast<const bf16x8*>(&krow[((0 + g) ^ (kj & 7)) * 8]);
        const bf16x8 kf1 = *reinterpret_cast<const bf16x8*>(&krow[((4 + g) ^ (kj & 7)) * 8]);
        f32x4 a = {};
        a = __builtin_amdgcn_mfma_f32_16x16x32_bf16(kf0, q2f0, a, 0, 0, 0);
        a = __builtin_amdgcn_mfma_f32_16x16x32_bf16(kf1, q2f1, a, 0, 0, 0);
        s2[nf] = a;
        f32x4 b = {};
        b = __builtin_amdgcn_mfma_f32_16x16x32_bf16(kf0, q1f0, b, 0, 0, 0);
        b = __builtin_amdgcn_mfma_f32_16x16x32_bf16(kf1, q1f1, b, 0, 0, 0);
        s1[nf] = b;
      }
      __builtin_amdgcn_s_setprio(0);
      if (t == qt1) maskdiag(s1, wave, cl, g);
      // softmax2 overlaps s1's MFMA tail; softmax1 overlaps PV2 issue
      u32 pk2[8], pk1[8];
      softmax_pk(s2, o2, m2, l2, g, pk2);
      softmax_pk(s1, o1, m1, l1, g, pk1);
      // ---- fused PV: each V frag read once, feeds both states ----
      __builtin_amdgcn_s_setprio(1);
#pragma unroll
      for (int fo = 0; fo < 4; fo++){
        const int d = fo * 16 + cl;
#pragma unroll
        for (int nf = 0; nf < 4; nf++){
          const bf16x4 vf = *reinterpret_cast<const bf16x4*>(
              &VtC[d * 64 + (((nf * 4 + g) ^ (d & 7)) << 2)]);
          union { u32 u[2]; bf16x4 v; } pa2, pa1;
          pa2.u[0] = pk2[2*nf]; pa2.u[1] = pk2[2*nf+1];
          pa1.u[0] = pk1[2*nf]; pa1.u[1] = pk1[2*nf+1];
          o2[fo] = mfma16(pa2.v, vf, o2[fo]);
          o1[fo] = mfma16(pa1.v, vf, o1[fo]);
        }
      }
      __builtin_amdgcn_s_setprio(0);
    } else {
      // ---- single-state body (state 2 only) ----
      f32x4 s[4];
      qkt(KsC, q2f0, q2f1, cl, g, s);
      if (t == qt2) maskdiag(s, wave, cl, g);
      sm_pv(s, o2, m2, l2, VtC, cl, g);
    }

    asm volatile("s_waitcnt lgkmcnt(0)" ::: "memory");   // all LDS reads of buf[cur] sampled
    __builtin_amdgcn_sched_barrier(0);
    __builtin_amdgcn_s_barrier();    // release buf[cur] for stage(t+2)
  }

  // ---- epilogue: O/l for both q-tiles -> attn_out [B,T,C] bf16 ----
  float li1[4], li2[4];
#pragma unroll
  for (int r = 0; r < 4; r++){
    li1[r] = 1.0f / __shfl(l1, g * 4 + r);
    li2[r] = 1.0f / __shfl(l2, g * 4 + r);
  }
  const int b = bh >> 4, h = bh & 15;
#pragma unroll
  for (int fo = 0; fo < 4; fo++){
#pragma unroll
    for (int r = 0; r < 4; r++){
      const int c = h * 64 + fo * 16 + cl;
      const int t1 = qt1 * 64 + wave * 16 + g * 4 + r;
      ao[((size_t)b * NT + t1) * NC + c] = f2bf(o1[fo][r] * li1[r]);
      const int t2 = qt2 * 64 + wave * 16 + g * 4 + r;
      ao[((size_t)b * NT + t2) * NC + c] = f2bf(o2[fo][r] * li2[r]);
    }
  }
}

extern "C" void kernel_launch(void* const* d_in, const int* in_sizes, int n_in,
                              void* d_out, int out_size, void* d_ws, size_t ws_size,
                              hipStream_t stream){
  const float* x      = (const float*)d_in[0];
  const float* w_qkv  = (const float*)d_in[1];
  const float* b_qkv  = (const float*)d_in[2];
  const float* w_proj = (const float*)d_in[3];
  const float* b_proj = (const float*)d_in[4];
  float* out = (float*)d_out;

  u16* ws = (u16*)d_ws;
  u16* xb     = ws;                 //  [B,T,C] bf16
  u16* qb     = ws + 8388608;       //  [B,H,T,D] standard
  u16* kb     = ws + 16777216;      //  [B,H] x tiles, swizzled
  u16* vb     = ws + 25165824;      //  [B,H] x tiles, transposed+swizzled
  u16* aob    = ws + 33554432;      //  [B,T,C]
  u16* wqkvT  = ws + 41943040;      //  [3C,C]
  u16* wprojT = ws + 45088768;      //  [C,C]

  k_cast<<<8388608 / 1024, 256, 0, stream>>>(x, xb);
  k_transpose_cast<<<dim3(N3C / 32, NC / 32), dim3(32, 8), 0, stream>>>(w_qkv, wqkvT, NC, N3C);
  k_transpose_cast<<<dim3(NC / 32, NC / 32), dim3(32, 8), 0, stream>>>(w_proj, wprojT, NC, NC);
  k_gemm_qkv<<<dim3(N3C / 128, NM / 128), 256, 0, stream>>>(xb, wqkvT, b_qkv, qb, kb, vb);
  k_flash<<<dim3(NQT / 2, NB * NH), 256, 0, stream>>>(qb, kb, vb, aob);
  k_gemm_proj<<<dim3(NC / 128, NM / 128), 256, 0, stream>>>(aob, wprojT, b_proj, out);
}

// Round 11
// 228.351 us; speedup vs baseline: 1.0273x; 1.0273x over previous
//
#include <hip/hip_runtime.h>
#include <cstdint>

typedef unsigned short u16;
typedef uint32_t u32;
typedef __attribute__((ext_vector_type(8))) short bf16x8;
typedef __attribute__((ext_vector_type(4))) short bf16x4;
typedef __attribute__((ext_vector_type(4))) float f32x4;

#define NB 4
#define NT 2048
#define NC 1024
#define NH 16
#define ND 64
#define NM (NB*NT)      // 8192
#define N3C (3*NC)      // 3072
#define NQT (NT/64)     // 32 q-tiles per (b,h)

// Q scale: 1/sqrt(64) * log2(e)  (softmax runs in log2 domain -> exp2)
#define QSCALE 0.18033688011112042f

static __device__ __forceinline__ u16 f2bf(float f){
  union { float f; uint32_t u; } v; v.f = f;
  return (u16)((v.u + 0x7fffu + ((v.u >> 16) & 1u)) >> 16);
}

// async 16B global->LDS (LDS dest is wave-uniform base + lane*16)
static __device__ __forceinline__ void gld_lds16(void* lds, const void* g){
  auto lp = reinterpret_cast<__attribute__((address_space(3))) uint32_t*>(
      reinterpret_cast<uintptr_t>(lds));
  auto gp = reinterpret_cast<__attribute__((address_space(1))) uint32_t*>(
      reinterpret_cast<uintptr_t>(g));
  __builtin_amdgcn_global_load_lds(gp, lp, 16, 0, 0);
}

static __device__ __forceinline__ f32x4 mfma16(bf16x4 a, bf16x4 b, f32x4 c){
#if __has_builtin(__builtin_amdgcn_mfma_f32_16x16x16bf16_1k)
  return __builtin_amdgcn_mfma_f32_16x16x16bf16_1k(a, b, c, 0, 0, 0);
#else
  asm("v_mfma_f32_16x16x16_bf16 %0, %1, %2, %0" : "+v"(c) : "v"(a), "v"(b));
  return c;
#endif
}

// ---------------- elementwise cast fp32 -> bf16 ----------------
__global__ __launch_bounds__(256) void k_cast(const float* __restrict__ in,
                                              u16* __restrict__ out){
  const int i = (blockIdx.x * 256 + threadIdx.x) * 4;
  const float4 vv = *reinterpret_cast<const float4*>(in + i);
  union { u16 s[4]; uint64_t u; } pk;
  pk.s[0] = f2bf(vv.x); pk.s[1] = f2bf(vv.y);
  pk.s[2] = f2bf(vv.z); pk.s[3] = f2bf(vv.w);
  *reinterpret_cast<uint64_t*>(out + i) = pk.u;
}

// ---------------- tiled transpose + cast: in[R][Cc] fp32 -> out[Cc][R] bf16 ----------------
__global__ __launch_bounds__(256) void k_transpose_cast(const float* __restrict__ in,
                                                        u16* __restrict__ out,
                                                        int R, int Cc){
  __shared__ float tile[32][33];
  const int bx = blockIdx.x * 32, by = blockIdx.y * 32;
  const int tx = threadIdx.x, ty = threadIdx.y;
#pragma unroll
  for (int i = 0; i < 32; i += 8)
    tile[ty + i][tx] = in[(size_t)(by + ty + i) * Cc + bx + tx];
  __syncthreads();
#pragma unroll
  for (int i = 0; i < 32; i += 8)
    out[(size_t)(bx + ty + i) * R + by + tx] = f2bf(tile[tx][ty + i]);
}

// ---------------- shared GEMM main loop: C[128x128] tile, A[M][K] * Bt[N][K]^T ----------------
static __device__ __forceinline__ void gemm_mainloop(
    const u16* __restrict__ A, const u16* __restrict__ Bt, int K,
    int m0, int n0, u16* As, u16* Bs, f32x4 acc[4][4])
{
  const int tid = threadIdx.x;
  const int wave = tid >> 6, lane = tid & 63;
  const int wm = wave >> 1, wn = wave & 1;
  const int o0 = tid * 8, o1 = o0 + 2048;           // elem offsets in the 128x32 tile
  const u16* Ag0 = A  + (size_t)(m0 + (o0 >> 5)) * K + (o0 & 31);
  const u16* Ag1 = A  + (size_t)(m0 + (o1 >> 5)) * K + (o1 & 31);
  const u16* Bg0 = Bt + (size_t)(n0 + (o0 >> 5)) * K + (o0 & 31);
  const u16* Bg1 = Bt + (size_t)(n0 + (o1 >> 5)) * K + (o1 & 31);
  u16* AsW = As + wave * 512;   // wave-uniform LDS base (1024 B per wave)
  u16* BsW = Bs + wave * 512;
  const int kb = (lane >> 4) * 8, rl = lane & 15;

  for (int kt = 0; kt < K; kt += 32){
    gld_lds16(AsW,        Ag0 + kt);
    gld_lds16(AsW + 2048, Ag1 + kt);
    gld_lds16(BsW,        Bg0 + kt);
    gld_lds16(BsW + 2048, Bg1 + kt);
    __syncthreads();
    bf16x8 af[4], bfr[4];
#pragma unroll
    for (int i = 0; i < 4; i++){
      af[i]  = *reinterpret_cast<const bf16x8*>(&As[(wm * 64 + i * 16 + rl) * 32 + kb]);
      bfr[i] = *reinterpret_cast<const bf16x8*>(&Bs[(wn * 64 + i * 16 + rl) * 32 + kb]);
    }
#pragma unroll
    for (int i = 0; i < 4; i++)
#pragma unroll
      for (int j = 0; j < 4; j++)
        acc[i][j] = __builtin_amdgcn_mfma_f32_16x16x32_bf16(af[i], bfr[j], acc[i][j], 0, 0, 0);
    __syncthreads();
  }
}

// ---------------- GEMM 1: x @ w_qkv + b_qkv -> Q (scaled), K (swizzled), V (transposed+swizzled) ----------------
// Q: [b,h,t,d] standard, values * QSCALE
// K: per (b,h): tile kt (4096 elems): (t&63)*64 + (d ^ ((t&7)<<3))
// V: per (b,h): tile kt (4096 elems): d*64 + (((t>>2)&15 ^ (d&7))<<2) + (t&3)   [transposed]
__global__ __launch_bounds__(256) void k_gemm_qkv(
    const u16* __restrict__ A, const u16* __restrict__ Bt,
    const float* __restrict__ bias,
    u16* __restrict__ qo, u16* __restrict__ ko, u16* __restrict__ vo)
{
  __shared__ u16 As[128 * 32], Bs[128 * 32];
  f32x4 acc[4][4] = {};
  const int m0 = blockIdx.y * 128, n0 = blockIdx.x * 128;
  gemm_mainloop(A, Bt, NC, m0, n0, As, Bs, acc);

  const int tid = threadIdx.x;
  const int wave = tid >> 6, lane = tid & 63;
  const int wm = wave >> 1, wn = wave & 1;
  const int rl = lane & 15, rg = lane >> 4;
  const int which = n0 >> 10;   // uniform per block: 0=Q 1=K 2=V
  if (which == 2){
    // V: pack 4 consecutive t (r=0..3, t&3=r) into one 8B store
#pragma unroll
    for (int j = 0; j < 4; j++){
      const int n = n0 + wn * 64 + j * 16 + rl;
      const int cc = n & 1023;
      const int h = cc >> 6, d = cc & 63;
      const float bb = bias[n];
#pragma unroll
      for (int i = 0; i < 4; i++){
        const int mb = m0 + wm * 64 + i * 16 + rg * 4;
        const int b = mb >> 11, t0 = mb & 2047;
        const size_t bhb = ((size_t)(b * NH + h)) * NT * ND;
        union { u16 s[4]; uint64_t u; } pk4;
#pragma unroll
        for (int r = 0; r < 4; r++) pk4.s[r] = f2bf(acc[i][j][r] + bb);
        *reinterpret_cast<uint64_t*>(
          &vo[bhb + (size_t)(t0 >> 6) * 4096 + d * 64 + ((((t0 >> 2) & 15) ^ (d & 7)) << 2)]) = pk4.u;
      }
    }
  } else {
#pragma unroll
    for (int j = 0; j < 4; j++){
      const int n = n0 + wn * 64 + j * 16 + rl;
      const int cc = n & 1023;
      const int h = cc >> 6, d = cc & 63;
      const float bb = bias[n];
#pragma unroll
      for (int i = 0; i < 4; i++){
#pragma unroll
        for (int r = 0; r < 4; r++){
          const int m = m0 + wm * 64 + i * 16 + rg * 4 + r;
          const int b = m >> 11, t = m & 2047;
          const size_t bhb = ((size_t)(b * NH + h)) * NT * ND;
          const float val = acc[i][j][r] + bb;
          if (which == 0){
            qo[bhb + (size_t)t * ND + d] = f2bf(val * QSCALE);
          } else {
            ko[bhb + (size_t)(t >> 6) * 4096 + (t & 63) * 64 + (d ^ ((t & 7) << 3))] = f2bf(val);
          }
        }
      }
    }
  }
}

// ---------------- GEMM 2: attn_out @ w_proj + b_proj -> fp32 out ----------------
__global__ __launch_bounds__(256) void k_gemm_proj(
    const u16* __restrict__ A, const u16* __restrict__ Bt,
    const float* __restrict__ bias, float* __restrict__ out)
{
  __shared__ u16 As[128 * 32], Bs[128 * 32];
  f32x4 acc[4][4] = {};
  const int m0 = blockIdx.y * 128, n0 = blockIdx.x * 128;
  gemm_mainloop(A, Bt, NC, m0, n0, As, Bs, acc);

  const int tid = threadIdx.x;
  const int wave = tid >> 6, lane = tid & 63;
  const int wm = wave >> 1, wn = wave & 1;
  const int rl = lane & 15, rg = lane >> 4;
#pragma unroll
  for (int i = 0; i < 4; i++){
#pragma unroll
    for (int r = 0; r < 4; r++){
      const int m = m0 + wm * 64 + i * 16 + rg * 4 + r;
#pragma unroll
      for (int j = 0; j < 4; j++){
        const int n = n0 + wn * 64 + j * 16 + rl;
        out[(size_t)m * NC + n] = acc[i][j][r] + bias[n];
      }
    }
  }
}

// ---------------- flash helpers (precomputed per-lane LDS bases; offsets are immediates) ----------------
// S^T = K Q^T : s[nf] holds S^T[k = nf*16 + g*4 + r][q = cl]
static __device__ __forceinline__ void qkt_p(const u16* kb0, const u16* kb1,
                                             bf16x8 qf0, bf16x8 qf1, f32x4 s[4])
{
  __builtin_amdgcn_s_setprio(1);
#pragma unroll
  for (int nf = 0; nf < 4; nf++){
    const bf16x8 kf0 = *reinterpret_cast<const bf16x8*>(kb0 + nf * 1024);
    const bf16x8 kf1 = *reinterpret_cast<const bf16x8*>(kb1 + nf * 1024);
    f32x4 a = {};
    a = __builtin_amdgcn_mfma_f32_16x16x32_bf16(kf0, qf0, a, 0, 0, 0);
    a = __builtin_amdgcn_mfma_f32_16x16x32_bf16(kf1, qf1, a, 0, 0, 0);
    s[nf] = a;
  }
  __builtin_amdgcn_s_setprio(0);
}

static __device__ __forceinline__ void maskdiag(f32x4 s[4], int wave, int cl, int g){
  const int qrl = wave * 16 + cl;
#pragma unroll
  for (int nf = 0; nf < 4; nf++)
#pragma unroll
    for (int r = 0; r < 4; r++)
      if (nf * 16 + g * 4 + r > qrl) s[nf][r] = -3e38f;
}

// online softmax (log2 domain, defer-max THR=8, tree reductions) + PV accumulate
static __device__ __forceinline__ void sm_pv_p(
    f32x4 s[4], f32x4 o[4], float& mrun, float& lrun,
    const u16* vp0, const u16* vp1, const u16* vp2, const u16* vp3, int g)
{
  // tree max (depth 4)
  const float t0 = fmaxf(fmaxf(s[0][0], s[0][1]), fmaxf(s[0][2], s[0][3]));
  const float t1 = fmaxf(fmaxf(s[1][0], s[1][1]), fmaxf(s[1][2], s[1][3]));
  const float t2 = fmaxf(fmaxf(s[2][0], s[2][1]), fmaxf(s[2][2], s[2][3]));
  const float t3 = fmaxf(fmaxf(s[3][0], s[3][1]), fmaxf(s[3][2], s[3][3]));
  float rmax = fmaxf(fmaxf(t0, t1), fmaxf(t2, t3));
  rmax = fmaxf(rmax, __shfl_xor(rmax, 16));
  rmax = fmaxf(rmax, __shfl_xor(rmax, 32));
  // defer-max: only rescale when the row max grew by >8 (P bounded by 2^8)
  if (!__all(rmax <= mrun + 8.0f)){
    const float mnew = fmaxf(mrun, rmax);
    const float alpha = exp2f(mrun - mnew);
    mrun = mnew;
    lrun *= alpha;
    const float a0 = __shfl(alpha, g * 4 + 0);
    const float a1 = __shfl(alpha, g * 4 + 1);
    const float a2 = __shfl(alpha, g * 4 + 2);
    const float a3 = __shfl(alpha, g * 4 + 3);
#pragma unroll
    for (int fo = 0; fo < 4; fo++){
      o[fo][0] *= a0; o[fo][1] *= a1; o[fo][2] *= a2; o[fo][3] *= a3;
    }
  }
#pragma unroll
  for (int nf = 0; nf < 4; nf++)
#pragma unroll
    for (int r = 0; r < 4; r++)
      s[nf][r] = exp2f(s[nf][r] - mrun);
  // tree sum
  const float u0 = (s[0][0] + s[0][1]) + (s[0][2] + s[0][3]);
  const float u1 = (s[1][0] + s[1][1]) + (s[1][2] + s[1][3]);
  const float u2 = (s[2][0] + s[2][1]) + (s[2][2] + s[2][3]);
  const float u3 = (s[3][0] + s[3][1]) + (s[3][2] + s[3][3]);
  float rs = (u0 + u1) + (u2 + u3);
  rs += __shfl_xor(rs, 16);
  rs += __shfl_xor(rs, 32);
  lrun += rs;

  u32 pk[8];
#pragma unroll
  for (int nf = 0; nf < 4; nf++){
    asm("v_cvt_pk_bf16_f32 %0, %1, %2" : "=v"(pk[2*nf  ]) : "v"(s[nf][0]), "v"(s[nf][1]));
    asm("v_cvt_pk_bf16_f32 %0, %1, %2" : "=v"(pk[2*nf+1]) : "v"(s[nf][2]), "v"(s[nf][3]));
  }
  const u16* vps[4] = { vp0, vp1, vp2, vp3 };
  __builtin_amdgcn_s_setprio(1);
#pragma unroll
  for (int nf = 0; nf < 4; nf++){
    union { u32 u[2]; bf16x4 v; } pa;
    pa.u[0] = pk[2*nf]; pa.u[1] = pk[2*nf+1];
#pragma unroll
    for (int fo = 0; fo < 4; fo++){
      const bf16x4 vf = *reinterpret_cast<const bf16x4*>(vps[nf] + fo * 1024);
      o[fo] = mfma16(pa.v, vf, o[fo]);
    }
  }
  __builtin_amdgcn_s_setprio(0);
}

// ---------------- causal flash attention: one KV sweep serves q-tiles {px, 31-px} ----------------
// Double-buffered staging, raw s_barrier + counted vmcnt. t-loop unrolled x2 so the LDS
// buffer index is a literal and all ds_read addresses fold to base-reg + immediate.
__global__ __launch_bounds__(256) void k_flash(
    const u16* __restrict__ q, const u16* __restrict__ k,
    const u16* __restrict__ v, u16* __restrict__ ao)
{
  __shared__ u16 Ks[2][4096];   // [buf][kj*64 + swz-d], 16B-chunk swizzle: chunk' = chunk ^ (kj&7)
  __shared__ u16 Vt[2][4096];   // [buf][d*64 + swz-kj], 8B-chunk swizzle
  const int tid = threadIdx.x, wave = tid >> 6, lane = tid & 63;
  const int cl = lane & 15, g = lane >> 4;
  const int cl7 = cl & 7;
  const int c0 = wave * 2;
  const int px = blockIdx.x, bh = blockIdx.y;
  const int qt1 = px, qt2 = NQT - 1 - px;
  const int ntot = qt2 + 1;
  const size_t base = (size_t)bh * NT * ND;
  const u16* kg0 = k + base;
  const u16* vg0 = v + base;

  // per-lane LDS read bases (loop-invariant: (kj&7)==cl7 since nf*16%8==0; same for d)
  const u16* kb0[2] = { &Ks[0][cl * 64 + (((0 + g) ^ cl7) << 3)],
                        &Ks[1][cl * 64 + (((0 + g) ^ cl7) << 3)] };
  const u16* kb1[2] = { &Ks[0][cl * 64 + (((4 + g) ^ cl7) << 3)],
                        &Ks[1][cl * 64 + (((4 + g) ^ cl7) << 3)] };
  const u16* vbp[2][4];
#pragma unroll
  for (int bf = 0; bf < 2; bf++)
#pragma unroll
    for (int nf = 0; nf < 4; nf++)
      vbp[bf][nf] = &Vt[bf][cl * 64 + (((nf * 4 + g) ^ cl7) << 2)];

  // Q frags for both tiles: lane holds Q[q=cl][d=g*8+j]
  bf16x8 q1f0, q1f1, q2f0, q2f1;
  {
    const u16* qr1 = q + base + (size_t)(qt1 * 64 + wave * 16 + cl) * ND;
    q1f0 = *reinterpret_cast<const bf16x8*>(qr1 + g * 8);
    q1f1 = *reinterpret_cast<const bf16x8*>(qr1 + 32 + g * 8);
    const u16* qr2 = q + base + (size_t)(qt2 * 64 + wave * 16 + cl) * ND;
    q2f0 = *reinterpret_cast<const bf16x8*>(qr2 + g * 8);
    q2f1 = *reinterpret_cast<const bf16x8*>(qr2 + 32 + g * 8);
  }
  asm volatile("" : "+v"(q1f0), "+v"(q1f1), "+v"(q2f0), "+v"(q2f1));

  f32x4 o1[4] = {}, o2[4] = {};
  float m1 = -1e30f, l1 = 0.f, m2 = -1e30f, l2 = 0.f;

#define STAGE(BUF, T)                                                          \
  {                                                                            \
    const u16* kg = kg0 + (size_t)(T) * 4096;                                  \
    const u16* vg = vg0 + (size_t)(T) * 4096;                                  \
    gld_lds16(&Ks[BUF][(c0    ) * 512], kg + (c0    ) * 512 + lane * 8);       \
    gld_lds16(&Ks[BUF][(c0 + 1) * 512], kg + (c0 + 1) * 512 + lane * 8);       \
    gld_lds16(&Vt[BUF][(c0    ) * 512], vg + (c0    ) * 512 + lane * 8);       \
    gld_lds16(&Vt[BUF][(c0 + 1) * 512], vg + (c0 + 1) * 512 + lane * 8);       \
  }

#define PROCESS(BUF, T)                                                        \
  {                                                                            \
    f32x4 s2x[4];                                                              \
    qkt_p(kb0[BUF], kb1[BUF], q2f0, q2f1, s2x);                                \
    if ((T) == qt2) maskdiag(s2x, wave, cl, g);                                \
    sm_pv_p(s2x, o2, m2, l2, vbp[BUF][0], vbp[BUF][1], vbp[BUF][2],            \
            vbp[BUF][3], g);                                                   \
    if ((T) <= qt1){                                                           \
      f32x4 s1x[4];                                                            \
      qkt_p(kb0[BUF], kb1[BUF], q1f0, q1f1, s1x);                              \
      if ((T) == qt1) maskdiag(s1x, wave, cl, g);                              \
      sm_pv_p(s1x, o1, m1, l1, vbp[BUF][0], vbp[BUF][1], vbp[BUF][2],          \
              vbp[BUF][3], g);                                                 \
    }                                                                          \
  }

  // prologue: stage tile 0 -> buf 0
  STAGE(0, 0);

  for (int t = 0; ; t += 2){
    // even phase: process buf0 = tile t, stage tile t+1 -> buf1
    if (t + 1 < ntot){
      STAGE(1, t + 1);
      asm volatile("s_waitcnt vmcnt(4)" ::: "memory");
    } else {
      asm volatile("s_waitcnt vmcnt(0)" ::: "memory");
    }
    __builtin_amdgcn_sched_barrier(0);
    __builtin_amdgcn_s_barrier();
    PROCESS(0, t);
    asm volatile("s_waitcnt lgkmcnt(0)" ::: "memory");
    __builtin_amdgcn_sched_barrier(0);
    __builtin_amdgcn_s_barrier();
    if (t + 1 >= ntot) break;

    // odd phase: process buf1 = tile t+1, stage tile t+2 -> buf0
    if (t + 2 < ntot){
      STAGE(0, t + 2);
      asm volatile("s_waitcnt vmcnt(4)" ::: "memory");
    } else {
      asm volatile("s_waitcnt vmcnt(0)" ::: "memory");
    }
    __builtin_amdgcn_sched_barrier(0);
    __builtin_amdgcn_s_barrier();
    PROCESS(1, t + 1);
    asm volatile("s_waitcnt lgkmcnt(0)" ::: "memory");
    __builtin_amdgcn_sched_barrier(0);
    __builtin_amdgcn_s_barrier();
    if (t + 2 >= ntot) break;
  }
#undef STAGE
#undef PROCESS

  // ---- epilogue: O/l for both q-tiles -> attn_out [B,T,C] bf16 ----
  float li1[4], li2[4];
#pragma unroll
  for (int r = 0; r < 4; r++){
    li1[r] = 1.0f / __shfl(l1, g * 4 + r);
    li2[r] = 1.0f / __shfl(l2, g * 4 + r);
  }
  const int b = bh >> 4, h = bh & 15;
#pragma unroll
  for (int fo = 0; fo < 4; fo++){
#pragma unroll
    for (int r = 0; r < 4; r++){
      const int c = h * 64 + fo * 16 + cl;
      const int t1 = qt1 * 64 + wave * 16 + g * 4 + r;
      ao[((size_t)b * NT + t1) * NC + c] = f2bf(o1[fo][r] * li1[r]);
      const int t2 = qt2 * 64 + wave * 16 + g * 4 + r;
      ao[((size_t)b * NT + t2) * NC + c] = f2bf(o2[fo][r] * li2[r]);
    }
  }
}

extern "C" void kernel_launch(void* const* d_in, const int* in_sizes, int n_in,
                              void* d_out, int out_size, void* d_ws, size_t ws_size,
                              hipStream_t stream){
  const float* x      = (const float*)d_in[0];
  const float* w_qkv  = (const float*)d_in[1];
  const float* b_qkv  = (const float*)d_in[2];
  const float* w_proj = (const float*)d_in[3];
  const float* b_proj = (const float*)d_in[4];
  float* out = (float*)d_out;

  u16* ws = (u16*)d_ws;
  u16* xb     = ws;                 //  [B,T,C] bf16
  u16* qb     = ws + 8388608;       //  [B,H,T,D] standard
  u16* kb     = ws + 16777216;      //  [B,H] x tiles, swizzled
  u16* vb     = ws + 25165824;      //  [B,H] x tiles, transposed+swizzled
  u16* aob    = ws + 33554432;      //  [B,T,C]
  u16* wqkvT  = ws + 41943040;      //  [3C,C]
  u16* wprojT = ws + 45088768;      //  [C,C]

  k_cast<<<8388608 / 1024, 256, 0, stream>>>(x, xb);
  k_transpose_cast<<<dim3(N3C / 32, NC / 32), dim3(32, 8), 0, stream>>>(w_qkv, wqkvT, NC, N3C);
  k_transpose_cast<<<dim3(NC / 32, NC / 32), dim3(32, 8), 0, stream>>>(w_proj, wprojT, NC, NC);
  k_gemm_qkv<<<dim3(N3C / 128, NM / 128), 256, 0, stream>>>(xb, wqkvT, b_qkv, qb, kb, vb);
  k_flash<<<dim3(NQT / 2, NB * NH), 256, 0, stream>>>(qb, kb, vb, aob);
  k_gemm_proj<<<dim3(NC / 128, NM / 128), 256, 0, stream>>>(aob, wprojT, b_proj, out);
}